// Round 12
// baseline (325.913 us; speedup 1.0000x reference)
//
#include <hip/hip_runtime.h>

typedef __attribute__((ext_vector_type(8))) short bf16x8;
typedef __attribute__((ext_vector_type(4))) float f32x4;
typedef __attribute__((ext_vector_type(4))) unsigned short u16x4;

#define GAS(p) ((const __attribute__((address_space(1))) void*)(p))
#define LAS(p) ((__attribute__((address_space(3))) void*)(p))

__device__ __forceinline__ unsigned short f2bf(float f) {
  unsigned int u = __float_as_uint(f);
  u += 0x7fffu + ((u >> 16) & 1u);
  return (unsigned short)(u >> 16);
}

__device__ __forceinline__ float bf2f(unsigned short u) {
  return __uint_as_float(((unsigned int)u) << 16);
}

__device__ __forceinline__ float fexp2(float x) {
  float r;
  asm("v_exp_f32 %0, %1" : "=v"(r) : "v"(x));
  return r;
}

// ---------------- fused f32 -> bf16 convert (all 7 tensors, 1 launch) ----------------
struct CvtArgs {
  const float *x, *wq, *wk, *wv, *wo, *w1, *w2;
  unsigned short *xb, *wqd, *wkd, *wvd, *wod, *w1d, *w2d;
};
__global__ __launch_bounds__(256) void k_convall(CvtArgs a) {
  long i = (long)blockIdx.x * 256 + threadIdx.x;  // vec4 index
  const float* s;
  unsigned short* d;
  long j;
  if (i < 1048576)      { s = a.x;  d = a.xb;  j = i; }
  else if (i < 1310720) { s = a.wq; d = a.wqd; j = i - 1048576; }
  else if (i < 1572864) { s = a.wk; d = a.wkd; j = i - 1310720; }
  else if (i < 1835008) { s = a.wv; d = a.wvd; j = i - 1572864; }
  else if (i < 2097152) { s = a.wo; d = a.wod; j = i - 1835008; }
  else if (i < 2621440) { s = a.w1; d = a.w1d; j = i - 2097152; }
  else                  { s = a.w2; d = a.w2d; j = i - 2621440; }
  f32x4 v = *(const f32x4*)(s + j * 4);
  u16x4 o;
  o[0] = f2bf(v[0]); o[1] = f2bf(v[1]); o[2] = f2bf(v[2]); o[3] = f2bf(v[3]);
  *(u16x4*)(d + j * 4) = o;
}

// ---------------- pack graph biases: u8 = (round(W*127)<<1) | (C>0.5) ----------------
__global__ __launch_bounds__(256)
void k_packwc(const float* __restrict__ Wm, const float* __restrict__ Cm,
              unsigned char* __restrict__ P) {
  long i = (long)blockIdx.x * 256 + threadIdx.x;  // vec4 index; 4096*4096/4 total
  f32x4 w = *(const f32x4*)(Wm + i * 4);
  f32x4 c = *(const f32x4*)(Cm + i * 4);
  unsigned int o = 0;
#pragma unroll
  for (int e = 0; e < 4; ++e) {
    unsigned int v = (unsigned int)(w[e] * 127.0f + 0.5f);
    o |= (((v << 1) | (c[e] > 0.5f ? 1u : 0u)) & 0xFFu) << (8 * e);
  }
  *(unsigned int*)(P + i * 4) = o;
}

// ---------------- bf16 GEMM: C[M,N] = A[M,K] * B[N,K]^T ------------------------------
template<int RELU, int OUTMODE, int BM>
__global__ __launch_bounds__(256, (BM == 64 ? 4 : 2))
void k_gemm_bt(const unsigned short* __restrict__ A, const unsigned short* __restrict__ B,
               const float* __restrict__ bias, void* __restrict__ C,
               int M, int N, int K, int ldc,
               void* __restrict__ C2 = nullptr, void* __restrict__ C3 = nullptr)
{
  __shared__ char sA[BM * 128];
  __shared__ char sB[128 * 128];
  const int t = threadIdx.x, wv = t >> 6, ln = t & 63;
  const int lr = ln & 15, lg = ln >> 4;
  const int m0 = blockIdx.y * BM, n0 = blockIdx.x * 128;
  const int wm = wv >> 1, wn = wv & 1;
  constexpr int MF = BM / 32;   // m-fragments per wave
  f32x4 acc[MF][4] = {};
  for (int k0 = 0; k0 < K; k0 += 64) {
#pragma unroll
    for (int c2 = 0; c2 < BM / 32; ++c2) {      // A chunks
      int p = ((c2 * 4 + wv) << 10) | (ln << 4);
      int row = p >> 7, colb = p & 127;
      const char* ga = (const char*)A + ((size_t)(m0 + row) * K + k0) * 2 + (colb ^ ((row & 7) << 4));
      __builtin_amdgcn_global_load_lds(GAS(ga), LAS(sA + ((c2 * 4 + wv) << 10)), 16, 0, 0);
    }
#pragma unroll
    for (int c2 = 0; c2 < 4; ++c2) {            // B chunks
      int p = ((c2 * 4 + wv) << 10) | (ln << 4);
      int row = p >> 7, colb = p & 127;
      const char* gb = (const char*)B + ((size_t)(n0 + row) * K + k0) * 2 + (colb ^ ((row & 7) << 4));
      __builtin_amdgcn_global_load_lds(GAS(gb), LAS(sB + ((c2 * 4 + wv) << 10)), 16, 0, 0);
    }
    __syncthreads();
#pragma unroll
    for (int kk = 0; kk < 2; ++kk) {
      bf16x8 af[MF], bfr[4];
#pragma unroll
      for (int i = 0; i < MF; ++i) {
        int row = wm * (BM / 2) + i * 16 + lr;
        af[i] = *(const bf16x8*)(sA + row * 128 + ((kk * 64 + lg * 16) ^ ((row & 7) << 4)));
      }
#pragma unroll
      for (int j = 0; j < 4; ++j) {
        int row = wn * 64 + j * 16 + lr;
        bfr[j] = *(const bf16x8*)(sB + row * 128 + ((kk * 64 + lg * 16) ^ ((row & 7) << 4)));
      }
#pragma unroll
      for (int i = 0; i < MF; ++i)
#pragma unroll
        for (int j = 0; j < 4; ++j)
          acc[i][j] = __builtin_amdgcn_mfma_f32_16x16x32_bf16(af[i], bfr[j], acc[i][j], 0, 0, 0);
    }
    __syncthreads();
  }
#pragma unroll
  for (int i = 0; i < MF; ++i) {
    int m = m0 + wm * (BM / 2) + i * 16 + lg * 4;
#pragma unroll
    for (int j = 0; j < 4; ++j) {
      int n = n0 + wn * 64 + j * 16 + lr;
      if (OUTMODE == 3) {
        if (n0 < 1024) {
#pragma unroll
          for (int r = 0; r < 4; ++r)
            ((unsigned short*)C)[(size_t)(m + r) * 1024 + n] = f2bf(acc[i][j][r]);
        } else if (n0 < 2048) {
#pragma unroll
          for (int r = 0; r < 4; ++r)
            ((unsigned short*)C2)[(size_t)(m + r) * 1024 + (n - 1024)] = f2bf(acc[i][j][r]);
        } else {
          u16x4 o;
#pragma unroll
          for (int r = 0; r < 4; ++r) o[r] = f2bf(acc[i][j][r]);
          *(u16x4*)((unsigned short*)C3 + (size_t)(n - 2048) * 4096 + m) = o;
        }
      } else if (OUTMODE == 2) {
        u16x4 o;
#pragma unroll
        for (int r = 0; r < 4; ++r) o[r] = f2bf(acc[i][j][r]);
        *(u16x4*)((unsigned short*)C + (size_t)n * ldc + m) = o;
      } else {
        float bv = bias ? bias[n] : 0.f;
#pragma unroll
        for (int r = 0; r < 4; ++r) {
          float v = acc[i][j][r] + bv;
          if (RELU) v = fmaxf(v, 0.f);
          if (OUTMODE == 1) ((unsigned short*)C)[(size_t)(m + r) * ldc + n] = f2bf(v);
          else ((float*)C)[(size_t)(m + r) * ldc + n] = v;
        }
      }
    }
  }
}

// ---------------- fused flash attention, split-KV, strength-reduced addressing -------
// grid (N/64, H, 2): block = 4 waves x 16 q rows, one KV-half (2048 = 64 tiles of 32).
// Persistent per-lane staging pointers (K +64KB/iter, V +64B/iter, bias +32/iter);
// unroll-2 loop makes both LDS buffer bases compile-time -> fragment addrs hoisted.
__global__ __launch_bounds__(256, 4)
void k_attn(const unsigned short* __restrict__ Qb, const unsigned short* __restrict__ Kb,
            const unsigned short* __restrict__ Vtb, const unsigned char* __restrict__ Pk,
            const float* __restrict__ bwv, const float* __restrict__ bcv,
            unsigned short* __restrict__ Opart, float* __restrict__ Ls)
{
  __shared__ char sK[2 * 8192];            // [buf][32 kv][256B d] bf16, xor-swizzled
  __shared__ char sV[2 * 8192];            // [buf][64 pairs][128B] bf16, xor-swizzled
  __shared__ unsigned short sP[4][16][44]; // pitch 44 -> disjoint bank octets per write
  const int t = threadIdx.x, wv = t >> 6, ln = t & 63;
  const int lr = ln & 15, lg = ln >> 4;
  const int h = blockIdx.y, z = blockIdx.z;
  const int q0 = blockIdx.x * 64 + wv * 16;
  const int kvb = z * 2048;
  const float L2E = 1.4426950408889634f;
  const float scaleL = 0.08838834764831845f * L2E; // (1/sqrt(128)) * log2e
  const float bw2 = bwv[h] * L2E * (1.0f / 127.0f), bc2 = bcv[h] * L2E;
  const float CL = 16.0f * L2E;

  // Q fragments (registers for whole kernel)
  bf16x8 qf[4];
#pragma unroll
  for (int kk = 0; kk < 4; ++kk)
    qf[kk] = *(const bf16x8*)(Qb + (size_t)(q0 + lr) * 1024 + h * 128 + kk * 32 + lg * 8);

  // persistent staging pointers + fixed LDS dest offsets
  const char* gK[2];
  const char* gV[2];
  int ldsOff[2];
#pragma unroll
  for (int c2 = 0; c2 < 2; ++c2) {
    int p = ((c2 * 4 + wv) << 10) | (ln << 4);
    ldsOff[c2] = p;
    {
      int row = p >> 8, colb = p & 255;   // K: 32 rows x 256B
      gK[c2] = (const char*)Kb + ((size_t)(kvb + row) * 1024 + h * 128) * 2 + (colb ^ ((row & 7) << 4));
    }
    {
      // V pair layout: pair=p>>7; slot s -> d = 2*pair+(s>>2), kv-chunk (s&3)*8
      int pair = p >> 7;
      int s = ((p & 127) ^ ((pair & 7) << 4)) >> 4;
      int d = 2 * pair + (s >> 2);
      int kvo = (s & 3) * 8;
      gV[c2] = (const char*)Vtb + ((size_t)(h * 128 + d) * 4096 + kvb + kvo) * 2;
    }
  }

  // persistent bias row pointers (advance +32/iter)
  const unsigned char* pk[4];
#pragma unroll
  for (int r = 0; r < 4; ++r)
    pk[r] = Pk + (size_t)(q0 + lg * 4 + r) * 4096 + lr + kvb;

  // fixed sP write/read bases
  unsigned short* sPw = &sP[wv][lg * 4][lr];
  const char* sPr = (const char*)sP[wv] + (size_t)lr * 88 + lg * 16;

  f32x4 Oacc[8] = {};
  float lsum[4] = {0.f, 0.f, 0.f, 0.f};

  auto stage = [&](int buf) {   // stages current pointers, then advances them
#pragma unroll
    for (int c2 = 0; c2 < 2; ++c2) {
      __builtin_amdgcn_global_load_lds(GAS(gK[c2]), LAS(sK + buf * 8192 + ldsOff[c2]), 16, 0, 0);
      __builtin_amdgcn_global_load_lds(GAS(gV[c2]), LAS(sV + buf * 8192 + ldsOff[c2]), 16, 0, 0);
      gK[c2] += 32 * 2048;  // next 32 kv rows
      gV[c2] += 64;         // next 32 kv cols
    }
  };

  // prologue: tile 0 -> buf 0
  stage(0);
  __syncthreads();

#pragma unroll 2
  for (int it = 0; it < 64; ++it) {
    const int cur = it & 1;
    const char* sKc = sK + cur * 8192;
    const char* sVc = sV + cur * 8192;

    // u8 bias loads for THIS tile (imm offsets 0 / 16 from 4 row pointers)
    unsigned char pv[2][4];
#pragma unroll
    for (int j = 0; j < 2; ++j)
#pragma unroll
      for (int r = 0; r < 4; ++r)
        pv[j][r] = pk[r][j * 16];
#pragma unroll
    for (int r = 0; r < 4; ++r) pk[r] += 32;

    // prefetch next K/V tile into the other buffers
    if (it < 63) stage(cur ^ 1);

    // S = Q K^T  (4 d-ksteps x 2 kv-ntiles)
    f32x4 S[2] = {};
    __builtin_amdgcn_s_setprio(1);
#pragma unroll
    for (int kk = 0; kk < 4; ++kk)
#pragma unroll
      for (int j = 0; j < 2; ++j) {
        int row = j * 16 + lr;
        bf16x8 kf = *(const bf16x8*)(sKc + row * 256 + ((kk * 64 + lg * 16) ^ ((row & 7) << 4)));
        S[j] = __builtin_amdgcn_mfma_f32_16x16x32_bf16(qf[kk], kf, S[j], 0, 0, 0);
      }
    __builtin_amdgcn_s_setprio(0);

    // softmax numerators: decode u8 bias, p = exp2(S*scaleL + fb); denominator
#pragma unroll
    for (int j = 0; j < 2; ++j)
#pragma unroll
      for (int r = 0; r < 4; ++r) {
        unsigned int v = pv[j][r];
        float w = (float)(v >> 1);
        float fb = fmaf(w, bw2, ((v & 1u) ? bc2 : 0.0f) - CL);
        float p = fexp2(fmaf(S[j][r], scaleL, fb));
        lsum[r] += p;
        sPw[r * 44 + j * 16] = f2bf(p);
      }

    // O += P V   (8 d-ntiles, single 32-k step) — conflict-free pair-layout reads
    __builtin_amdgcn_s_setprio(1);
    {
      bf16x8 pf = *(const bf16x8*)sPr;
#pragma unroll
      for (int n = 0; n < 8; ++n) {
        int row = n * 16 + lr;
        int pair = row >> 1;
        int slot = (((row & 1) << 2) + lg) ^ (pair & 7);
        bf16x8 vf = *(const bf16x8*)(sVc + pair * 128 + slot * 16);
        Oacc[n] = __builtin_amdgcn_mfma_f32_16x16x32_bf16(pf, vf, Oacc[n], 0, 0, 0);
      }
    }
    __builtin_amdgcn_s_setprio(0);

    __syncthreads();  // staging(t+1) drained (full-iter cover); cur-buffer reads done
  }

  // partial denominator reduce across the 16 lanes of each row group
#pragma unroll
  for (int r = 0; r < 4; ++r) {
#pragma unroll
    for (int msk = 1; msk < 16; msk <<= 1) lsum[r] += __shfl_xor(lsum[r], msk, 64);
  }

  // store unnormalized bf16 partial O + f32 partial lsum
  unsigned short* Op = Opart + (size_t)z * 4194304;
#pragma unroll
  for (int n = 0; n < 8; ++n)
#pragma unroll
    for (int r = 0; r < 4; ++r) {
      int qg = q0 + lg * 4 + r;
      Op[(size_t)qg * 1024 + h * 128 + n * 16 + lr] = f2bf(Oacc[n][r]);
    }
  if (lr == 0) {
#pragma unroll
    for (int r = 0; r < 4; ++r)
      Ls[(size_t)(z * 8 + h) * 4096 + q0 + lg * 4 + r] = lsum[r];
  }
}

// ---------------- combine split-KV partials: O = (O0+O1)/(l0+l1) (in-place safe) -----
__global__ __launch_bounds__(256)
void k_comb(const unsigned short* __restrict__ P, const float* __restrict__ Ls,
            unsigned short* __restrict__ out)
{
  const int q = blockIdx.x, t = threadIdx.x;
  const int h = t >> 5;
  float l = Ls[(size_t)h * 4096 + q] + Ls[(size_t)(8 + h) * 4096 + q];
  float inv = 1.0f / l;
  size_t o = (size_t)q * 1024 + t * 4;
  u16x4 a = *(const u16x4*)(P + o);
  u16x4 b = *(const u16x4*)(P + 4194304 + o);
  u16x4 c;
#pragma unroll
  for (int e = 0; e < 4; ++e) c[e] = f2bf((bf2f(a[e]) + bf2f(b[e])) * inv);
  *(u16x4*)(out + o) = c;
}

// ---------------- fused residual + LayerNorm (f32 out + optional bf16 out) -----------
__global__ __launch_bounds__(256, 4)
void k_ln(const float* __restrict__ resid, const float* __restrict__ delta,
          const float* __restrict__ g, const float* __restrict__ b,
          float* __restrict__ outf, unsigned short* __restrict__ outb)
{
  const int row = blockIdx.x, t = threadIdx.x;
  const float* pr = resid + (size_t)row * 1024;
  const float* pd = delta + (size_t)row * 1024;
  f32x4 a = *(const f32x4*)(pr + t * 4);
  f32x4 d = *(const f32x4*)(pd + t * 4);
  f32x4 x;
#pragma unroll
  for (int e = 0; e < 4; ++e) x[e] = a[e] + d[e];
  float s = x[0] + x[1] + x[2] + x[3];
  float ss = x[0]*x[0] + x[1]*x[1] + x[2]*x[2] + x[3]*x[3];
#pragma unroll
  for (int msk = 1; msk < 64; msk <<= 1) {
    s += __shfl_xor(s, msk, 64);
    ss += __shfl_xor(ss, msk, 64);
  }
  __shared__ float red[8];
  if ((t & 63) == 0) { red[(t >> 6) * 2] = s; red[(t >> 6) * 2 + 1] = ss; }
  __syncthreads();
  s = red[0] + red[2] + red[4] + red[6];
  ss = red[1] + red[3] + red[5] + red[7];
  float mu = s * (1.f / 1024.f);
  float var = ss * (1.f / 1024.f) - mu * mu;
  float rstd = rsqrtf(var + 1e-5f);
#pragma unroll
  for (int e = 0; e < 4; ++e) {
    int c = t * 4 + e;
    float y = (x[e] - mu) * rstd * g[c] + b[c];
    outf[(size_t)row * 1024 + c] = y;
    if (outb) outb[(size_t)row * 1024 + c] = f2bf(y);
  }
}

// ---------------- launch ----------------
extern "C" void kernel_launch(void* const* d_in, const int* in_sizes, int n_in,
                              void* d_out, int out_size, void* d_ws, size_t ws_size,
                              hipStream_t stream) {
  const float* x   = (const float*)d_in[0];
  const float* Wm  = (const float*)d_in[1];
  const float* Cm  = (const float*)d_in[2];
  const float* Wq  = (const float*)d_in[3];
  const float* Wk  = (const float*)d_in[4];
  const float* Wv  = (const float*)d_in[5];
  const float* Wo  = (const float*)d_in[6];
  const float* bo  = (const float*)d_in[7];
  const float* bw  = (const float*)d_in[8];
  const float* bc  = (const float*)d_in[9];
  const float* g1  = (const float*)d_in[10];
  const float* be1 = (const float*)d_in[11];
  const float* g2  = (const float*)d_in[12];
  const float* be2 = (const float*)d_in[13];
  const float* W1  = (const float*)d_in[14];
  const float* b1  = (const float*)d_in[15];
  const float* W2  = (const float*)d_in[16];
  const float* b2  = (const float*)d_in[17];

  char* ws = (char*)d_ws;
  const size_t MB = 1u << 20;
  unsigned short* xb   = (unsigned short*)(ws);            // 8MB  (later reused as x1b)
  unsigned short* Wqkv = (unsigned short*)(ws + 8  * MB);  // 6MB stacked [3072][1024]
  unsigned short* Wob  = (unsigned short*)(ws + 14 * MB);  // 2MB
  unsigned short* W1b  = (unsigned short*)(ws + 16 * MB);  // 4MB
  unsigned short* W2b  = (unsigned short*)(ws + 20 * MB);  // 4MB
  unsigned short* Qb   = (unsigned short*)(ws + 24 * MB);  // 8MB
  unsigned short* Kb   = (unsigned short*)(ws + 32 * MB);  // 8MB
  unsigned short* Vtb  = (unsigned short*)(ws + 40 * MB);  // 8MB, V TRANSPOSED [1024][4096]
  unsigned short* Obuf = (unsigned short*)(ws + 48 * MB);  // 16MB as Opart[2][4096][1024]
  float*          Lsb  = (float*)(ws + 64 * MB);           // 256KB lsum partials
  unsigned char*  Pkb  = (unsigned char*)(ws + 72 * MB);   // 16MB packed u8 W|C bias
  float*          tmp  = (float*)(ws + 56 * MB);           // 16MB (Wo out, then FF2 out)
  float*          x1f  = (float*)(ws + 24 * MB);           // 16MB (over Qb/Kb, dead by then)
  unsigned short* x1b  = (unsigned short*)(ws);            // over xb (dead)
  unsigned short* hb   = (unsigned short*)(ws + 40 * MB);  // 16MB (over Vtb/Obuf, dead)

  // 1. bf16 conversions + u8 graph-bias packing
  CvtArgs ca;
  ca.x = x; ca.wq = Wq; ca.wk = Wk; ca.wv = Wv; ca.wo = Wo; ca.w1 = W1; ca.w2 = W2;
  ca.xb = xb; ca.wqd = Wqkv; ca.wkd = Wqkv + 1024 * 1024; ca.wvd = Wqkv + 2048 * 1024;
  ca.wod = Wob; ca.w1d = W1b; ca.w2d = W2b;
  k_convall<<<12288, 256, 0, stream>>>(ca);
  k_packwc<<<16384, 256, 0, stream>>>(Wm, Cm, Pkb);

  // 2. fused QKV projection: cols 0-1023 -> Qb, 1024-2047 -> Kb, 2048-3071 -> Vt^T
  k_gemm_bt<0,3,128><<<dim3(24, 32), 256, 0, stream>>>(xb, Wqkv, nullptr, Qb,
                                                       4096, 3072, 1024, 1024, Kb, Vtb);

  // 3. fused attention, split-KV (z = 2 halves), 4 blocks/CU, then combine
  k_attn<<<dim3(64, 8, 2), 256, 0, stream>>>(Qb, Kb, Vtb, Pkb, bw, bc, Obuf, Lsb);
  k_comb<<<4096, 256, 0, stream>>>(Obuf, Lsb, Obuf);

  // 4. output projection (f32 out + bias) — BM=64 tile: grid 512 = 2 blocks/CU
  k_gemm_bt<0,0,64><<<dim3(8, 64), 256, 0, stream>>>(Obuf, Wob, bo, tmp, 4096, 1024, 1024, 1024);

  // 5. LN1: x1 = LN(x + attn_out)
  k_ln<<<4096, 256, 0, stream>>>(x, tmp, g1, be1, x1f, x1b);

  // 6. FF1 with ReLU (bf16 out) — BM=64: grid 1024 = 4 blocks/CU
  k_gemm_bt<1,1,64><<<dim3(16, 64), 256, 0, stream>>>(x1b, W1b, b1, hb, 4096, 2048, 1024, 2048);

  // 7. FF2 (f32 out) — BM=64: grid 512 = 2 blocks/CU
  k_gemm_bt<0,0,64><<<dim3(8, 64), 256, 0, stream>>>(hb, W2b, b2, tmp, 4096, 1024, 2048, 1024);

  // 8. LN2 -> d_out
  k_ln<<<4096, 256, 0, stream>>>(x1f, tmp, g2, be2, (float*)d_out, nullptr);
}

// Round 14
// 309.640 us; speedup vs baseline: 1.0526x; 1.0526x over previous
//
#include <hip/hip_runtime.h>

typedef __attribute__((ext_vector_type(8))) short bf16x8;
typedef __attribute__((ext_vector_type(4))) float f32x4;
typedef __attribute__((ext_vector_type(4))) unsigned short u16x4;

#define GAS(p) ((const __attribute__((address_space(1))) void*)(p))
#define LAS(p) ((__attribute__((address_space(3))) void*)(p))

__device__ __forceinline__ unsigned short f2bf(float f) {
  unsigned int u = __float_as_uint(f);
  u += 0x7fffu + ((u >> 16) & 1u);
  return (unsigned short)(u >> 16);
}

__device__ __forceinline__ float bf2f(unsigned short u) {
  return __uint_as_float(((unsigned int)u) << 16);
}

__device__ __forceinline__ float fexp2(float x) {
  float r;
  asm("v_exp_f32 %0, %1" : "=v"(r) : "v"(x));
  return r;
}

// -------- fused prep: 7x f32->bf16 convert + u8 graph-bias pack, ONE launch ----------
// Conv vec4 items: x 1048576 | wq/wk/wv/wo 262144 ea | w1 524288 | w2 524288
//   -> conv total 3,145,728. Pack items 4,194,304. Grand total 7,340,032 = 28672 x 256.
struct PrepArgs {
  const float *x, *wq, *wk, *wv, *wo, *w1, *w2, *wm, *cm;
  unsigned short *xb, *wqd, *wkd, *wvd, *wod, *w1d, *w2d;
  unsigned char *pk;
};
__global__ __launch_bounds__(256) void k_prep(PrepArgs a) {
  long i = (long)blockIdx.x * 256 + threadIdx.x;  // vec4 index
  if (i >= 3145728) {                             // pack segment
    long j = i - 3145728;
    f32x4 w = *(const f32x4*)(a.wm + j * 4);
    f32x4 c = *(const f32x4*)(a.cm + j * 4);
    unsigned int o = 0;
#pragma unroll
    for (int e = 0; e < 4; ++e) {
      unsigned int v = (unsigned int)(w[e] * 127.0f + 0.5f);
      o |= (((v << 1) | (c[e] > 0.5f ? 1u : 0u)) & 0xFFu) << (8 * e);
    }
    *(unsigned int*)(a.pk + j * 4) = o;
    return;
  }
  const float* s;
  unsigned short* d;
  long j;
  if (i < 1048576)      { s = a.x;  d = a.xb;  j = i; }
  else if (i < 1310720) { s = a.wq; d = a.wqd; j = i - 1048576; }
  else if (i < 1572864) { s = a.wk; d = a.wkd; j = i - 1310720; }
  else if (i < 1835008) { s = a.wv; d = a.wvd; j = i - 1572864; }
  else if (i < 2097152) { s = a.wo; d = a.wod; j = i - 1835008; }
  else if (i < 2621440) { s = a.w1; d = a.w1d; j = i - 2097152; }
  else                  { s = a.w2; d = a.w2d; j = i - 2621440; }
  f32x4 v = *(const f32x4*)(s + j * 4);
  u16x4 o;
  o[0] = f2bf(v[0]); o[1] = f2bf(v[1]); o[2] = f2bf(v[2]); o[3] = f2bf(v[3]);
  *(u16x4*)(d + j * 4) = o;
}

// ---------------- bf16 GEMM: C[M,N] = A[M,K] * B[N,K]^T ------------------------------
// Tile BM x 128, BK=64, 4 waves in 2x2 (wave tile BM/2 x 64).
// OUTMODE: 0 = f32 (+bias, relu opt), 1 = bf16 (+bias/relu opt), 2 = bf16 TRANSPOSED,
//          3 = QKV router: cols [0,1024)->C, [1024,2048)->C2, [2048,3072)->C3 transposed.
template<int RELU, int OUTMODE, int BM>
__global__ __launch_bounds__(256, (BM == 64 ? 4 : 2))
void k_gemm_bt(const unsigned short* __restrict__ A, const unsigned short* __restrict__ B,
               const float* __restrict__ bias, void* __restrict__ C,
               int M, int N, int K, int ldc,
               void* __restrict__ C2 = nullptr, void* __restrict__ C3 = nullptr)
{
  __shared__ char sA[BM * 128];
  __shared__ char sB[128 * 128];
  const int t = threadIdx.x, wv = t >> 6, ln = t & 63;
  const int lr = ln & 15, lg = ln >> 4;
  const int m0 = blockIdx.y * BM, n0 = blockIdx.x * 128;
  const int wm = wv >> 1, wn = wv & 1;
  constexpr int MF = BM / 32;   // m-fragments per wave
  f32x4 acc[MF][4] = {};
  for (int k0 = 0; k0 < K; k0 += 64) {
#pragma unroll
    for (int c2 = 0; c2 < BM / 32; ++c2) {      // A chunks
      int p = ((c2 * 4 + wv) << 10) | (ln << 4);
      int row = p >> 7, colb = p & 127;
      const char* ga = (const char*)A + ((size_t)(m0 + row) * K + k0) * 2 + (colb ^ ((row & 7) << 4));
      __builtin_amdgcn_global_load_lds(GAS(ga), LAS(sA + ((c2 * 4 + wv) << 10)), 16, 0, 0);
    }
#pragma unroll
    for (int c2 = 0; c2 < 4; ++c2) {            // B chunks
      int p = ((c2 * 4 + wv) << 10) | (ln << 4);
      int row = p >> 7, colb = p & 127;
      const char* gb = (const char*)B + ((size_t)(n0 + row) * K + k0) * 2 + (colb ^ ((row & 7) << 4));
      __builtin_amdgcn_global_load_lds(GAS(gb), LAS(sB + ((c2 * 4 + wv) << 10)), 16, 0, 0);
    }
    __syncthreads();
#pragma unroll
    for (int kk = 0; kk < 2; ++kk) {
      bf16x8 af[MF], bfr[4];
#pragma unroll
      for (int i = 0; i < MF; ++i) {
        int row = wm * (BM / 2) + i * 16 + lr;
        af[i] = *(const bf16x8*)(sA + row * 128 + ((kk * 64 + lg * 16) ^ ((row & 7) << 4)));
      }
#pragma unroll
      for (int j = 0; j < 4; ++j) {
        int row = wn * 64 + j * 16 + lr;
        bfr[j] = *(const bf16x8*)(sB + row * 128 + ((kk * 64 + lg * 16) ^ ((row & 7) << 4)));
      }
#pragma unroll
      for (int i = 0; i < MF; ++i)
#pragma unroll
        for (int j = 0; j < 4; ++j)
          acc[i][j] = __builtin_amdgcn_mfma_f32_16x16x32_bf16(af[i], bfr[j], acc[i][j], 0, 0, 0);
    }
    __syncthreads();
  }
#pragma unroll
  for (int i = 0; i < MF; ++i) {
    int m = m0 + wm * (BM / 2) + i * 16 + lg * 4;
#pragma unroll
    for (int j = 0; j < 4; ++j) {
      int n = n0 + wn * 64 + j * 16 + lr;
      if (OUTMODE == 3) {
        if (n0 < 1024) {
#pragma unroll
          for (int r = 0; r < 4; ++r)
            ((unsigned short*)C)[(size_t)(m + r) * 1024 + n] = f2bf(acc[i][j][r]);
        } else if (n0 < 2048) {
#pragma unroll
          for (int r = 0; r < 4; ++r)
            ((unsigned short*)C2)[(size_t)(m + r) * 1024 + (n - 1024)] = f2bf(acc[i][j][r]);
        } else {
          u16x4 o;
#pragma unroll
          for (int r = 0; r < 4; ++r) o[r] = f2bf(acc[i][j][r]);
          *(u16x4*)((unsigned short*)C3 + (size_t)(n - 2048) * 4096 + m) = o;
        }
      } else if (OUTMODE == 2) {
        u16x4 o;
#pragma unroll
        for (int r = 0; r < 4; ++r) o[r] = f2bf(acc[i][j][r]);
        *(u16x4*)((unsigned short*)C + (size_t)n * ldc + m) = o;
      } else {
        float bv = bias ? bias[n] : 0.f;
#pragma unroll
        for (int r = 0; r < 4; ++r) {
          float v = acc[i][j][r] + bv;
          if (RELU) v = fmaxf(v, 0.f);
          if (OUTMODE == 1) ((unsigned short*)C)[(size_t)(m + r) * ldc + n] = f2bf(v);
          else ((float*)C)[(size_t)(m + r) * ldc + n] = v;
        }
      }
    }
  }
}

// ---------------- fused flash attention, split-KV, u8 graph bias (R11 config) --------
// grid (N/64, H, 2): block = 4 waves x 16 q rows, one KV-half (2048 = 64 tiles of 32).
// K [32][256B] 8-slot swizzle; V PAIR layout [64 pairs][128B], 8-slot swizzle ->
// conflict-free vf reads. Bias 1 byte/elem (per-XCD slice L2-resident).
// Fixed-shift softmax (C=16); partial O + lsum per half, k_comb joins.
__global__ __launch_bounds__(256, 4)
void k_attn(const unsigned short* __restrict__ Qb, const unsigned short* __restrict__ Kb,
            const unsigned short* __restrict__ Vtb, const unsigned char* __restrict__ Pk,
            const float* __restrict__ bwv, const float* __restrict__ bcv,
            unsigned short* __restrict__ Opart, float* __restrict__ Ls)
{
  __shared__ char sK[2 * 8192];            // [buf][32 kv][256B d] bf16, xor-swizzled
  __shared__ char sV[2 * 8192];            // [buf][64 pairs][128B] bf16, xor-swizzled
  __shared__ unsigned short sP[4][16][44]; // pitch 44 -> disjoint bank octets per write
  const int t = threadIdx.x, wv = t >> 6, ln = t & 63;
  const int lr = ln & 15, lg = ln >> 4;
  const int h = blockIdx.y, z = blockIdx.z;
  const int q0 = blockIdx.x * 64 + wv * 16;
  const int kvb = z * 2048;
  const float L2E = 1.4426950408889634f;
  const float scaleL = 0.08838834764831845f * L2E; // (1/sqrt(128)) * log2e
  const float bw2 = bwv[h] * L2E * (1.0f / 127.0f), bc2 = bcv[h] * L2E;
  const float CL = 16.0f * L2E;

  // Q fragments (registers for whole kernel)
  bf16x8 qf[4];
#pragma unroll
  for (int kk = 0; kk < 4; ++kk)
    qf[kk] = *(const bf16x8*)(Qb + (size_t)(q0 + lr) * 1024 + h * 128 + kk * 32 + lg * 8);

  // per-row packed-bias pointers
  const unsigned char* pk[4];
#pragma unroll
  for (int r = 0; r < 4; ++r)
    pk[r] = Pk + (size_t)(q0 + lg * 4 + r) * 4096 + lr;

  f32x4 Oacc[8] = {};
  float lsum[4] = {0.f, 0.f, 0.f, 0.f};

  auto stageKV = [&](int buf, int kv) {
#pragma unroll
    for (int c2 = 0; c2 < 2; ++c2) {
      int p = ((c2 * 4 + wv) << 10) | (ln << 4);
      {
        int row = p >> 8, colb = p & 255;   // K: 32 rows x 256B
        const char* g = (const char*)Kb + ((size_t)(kv + row) * 1024 + h * 128) * 2 + (colb ^ ((row & 7) << 4));
        __builtin_amdgcn_global_load_lds(GAS(g), LAS(sK + buf * 8192 + p), 16, 0, 0);
      }
      {
        // V pair layout: pair=p>>7; slot s -> d = 2*pair+(s>>2), kv-chunk (s&3)*8
        int pair = p >> 7;
        int s = ((p & 127) ^ ((pair & 7) << 4)) >> 4;
        int d = 2 * pair + (s >> 2);
        int kvo = (s & 3) * 8;
        const char* g = (const char*)Vtb + ((size_t)(h * 128 + d) * 4096 + kv + kvo) * 2;
        __builtin_amdgcn_global_load_lds(GAS(g), LAS(sV + buf * 8192 + p), 16, 0, 0);
      }
    }
  };

  // prologue
  stageKV(0, kvb);
  __syncthreads();

  for (int it = 0; it < 64; ++it) {
    const int cur = it & 1;
    const int kv0 = kvb + (it << 5);
    const char* sKc = sK + cur * 8192;
    const char* sVc = sV + cur * 8192;

    // u8 bias loads for THIS tile, issued first (latency hides under QK^T MFMA)
    unsigned char pv[2][4];
#pragma unroll
    for (int j = 0; j < 2; ++j)
#pragma unroll
      for (int r = 0; r < 4; ++r)
        pv[j][r] = pk[r][kv0 + j * 16];

    // prefetch next K/V tile into the other buffers
    if (it < 63) stageKV(cur ^ 1, kv0 + 32);

    // S = Q K^T  (4 d-ksteps x 2 kv-ntiles)
    f32x4 S[2] = {};
    __builtin_amdgcn_s_setprio(1);
#pragma unroll
    for (int kk = 0; kk < 4; ++kk)
#pragma unroll
      for (int j = 0; j < 2; ++j) {
        int row = j * 16 + lr;
        bf16x8 kf = *(const bf16x8*)(sKc + row * 256 + ((kk * 64 + lg * 16) ^ ((row & 7) << 4)));
        S[j] = __builtin_amdgcn_mfma_f32_16x16x32_bf16(qf[kk], kf, S[j], 0, 0, 0);
      }
    __builtin_amdgcn_s_setprio(0);

    // softmax numerators: decode u8 bias, p = exp2(S*scaleL + fb); denominator
#pragma unroll
    for (int j = 0; j < 2; ++j)
#pragma unroll
      for (int r = 0; r < 4; ++r) {
        unsigned int v = pv[j][r];
        float w = (float)(v >> 1);
        float fb = fmaf(w, bw2, ((v & 1u) ? bc2 : 0.0f) - CL);
        float p = fexp2(fmaf(S[j][r], scaleL, fb));
        lsum[r] += p;
        sP[wv][lg * 4 + r][j * 16 + lr] = f2bf(p);
      }

    // O += P V   (8 d-ntiles, single 32-k step) — conflict-free pair-layout reads
    __builtin_amdgcn_s_setprio(1);
    {
      bf16x8 pf = *(const bf16x8*)((const char*)sP[wv] + (size_t)lr * 88 + lg * 16);
#pragma unroll
      for (int n = 0; n < 8; ++n) {
        int row = n * 16 + lr;
        int pair = row >> 1;
        int slot = (((row & 1) << 2) + lg) ^ (pair & 7);
        bf16x8 vf = *(const bf16x8*)(sVc + pair * 128 + slot * 16);
        Oacc[n] = __builtin_amdgcn_mfma_f32_16x16x32_bf16(pf, vf, Oacc[n], 0, 0, 0);
      }
    }
    __builtin_amdgcn_s_setprio(0);

    __syncthreads();  // staging(t+1) drained (full-iter cover); cur-buffer reads done
  }

  // partial denominator reduce across the 16 lanes of each row group
#pragma unroll
  for (int r = 0; r < 4; ++r) {
#pragma unroll
    for (int msk = 1; msk < 16; msk <<= 1) lsum[r] += __shfl_xor(lsum[r], msk, 64);
  }

  // store unnormalized bf16 partial O + f32 partial lsum
  unsigned short* Op = Opart + (size_t)z * 4194304;
#pragma unroll
  for (int n = 0; n < 8; ++n)
#pragma unroll
    for (int r = 0; r < 4; ++r) {
      int qg = q0 + lg * 4 + r;
      Op[(size_t)qg * 1024 + h * 128 + n * 16 + lr] = f2bf(Oacc[n][r]);
    }
  if (lr == 0) {
#pragma unroll
    for (int r = 0; r < 4; ++r)
      Ls[(size_t)(z * 8 + h) * 4096 + q0 + lg * 4 + r] = lsum[r];
  }
}

// ---------------- combine split-KV partials: O = (O0+O1)/(l0+l1) (in-place safe) -----
__global__ __launch_bounds__(256)
void k_comb(const unsigned short* __restrict__ P, const float* __restrict__ Ls,
            unsigned short* __restrict__ out)
{
  const int q = blockIdx.x, t = threadIdx.x;
  const int h = t >> 5;
  float l = Ls[(size_t)h * 4096 + q] + Ls[(size_t)(8 + h) * 4096 + q];
  float inv = 1.0f / l;
  size_t o = (size_t)q * 1024 + t * 4;
  u16x4 a = *(const u16x4*)(P + o);
  u16x4 b = *(const u16x4*)(P + 4194304 + o);
  u16x4 c;
#pragma unroll
  for (int e = 0; e < 4; ++e) c[e] = f2bf((bf2f(a[e]) + bf2f(b[e])) * inv);
  *(u16x4*)(out + o) = c;
}

// ---------- fused residual + LayerNorm: f32 resid + bf16 delta -> f32/bf16 out -------
__global__ __launch_bounds__(256, 4)
void k_ln(const float* __restrict__ resid, const unsigned short* __restrict__ delta,
          const float* __restrict__ g, const float* __restrict__ b,
          float* __restrict__ outf, unsigned short* __restrict__ outb)
{
  const int row = blockIdx.x, t = threadIdx.x;
  const float* pr = resid + (size_t)row * 1024;
  const unsigned short* pd = delta + (size_t)row * 1024;
  f32x4 a = *(const f32x4*)(pr + t * 4);
  u16x4 d = *(const u16x4*)(pd + t * 4);
  f32x4 x;
#pragma unroll
  for (int e = 0; e < 4; ++e) x[e] = a[e] + bf2f(d[e]);
  float s = x[0] + x[1] + x[2] + x[3];
  float ss = x[0]*x[0] + x[1]*x[1] + x[2]*x[2] + x[3]*x[3];
#pragma unroll
  for (int msk = 1; msk < 64; msk <<= 1) {
    s += __shfl_xor(s, msk, 64);
    ss += __shfl_xor(ss, msk, 64);
  }
  __shared__ float red[8];
  if ((t & 63) == 0) { red[(t >> 6) * 2] = s; red[(t >> 6) * 2 + 1] = ss; }
  __syncthreads();
  s = red[0] + red[2] + red[4] + red[6];
  ss = red[1] + red[3] + red[5] + red[7];
  float mu = s * (1.f / 1024.f);
  float var = ss * (1.f / 1024.f) - mu * mu;
  float rstd = rsqrtf(var + 1e-5f);
#pragma unroll
  for (int e = 0; e < 4; ++e) {
    int c = t * 4 + e;
    float y = (x[e] - mu) * rstd * g[c] + b[c];
    outf[(size_t)row * 1024 + c] = y;
    if (outb) outb[(size_t)row * 1024 + c] = f2bf(y);
  }
}

// ---------------- launch ----------------
extern "C" void kernel_launch(void* const* d_in, const int* in_sizes, int n_in,
                              void* d_out, int out_size, void* d_ws, size_t ws_size,
                              hipStream_t stream) {
  const float* x   = (const float*)d_in[0];
  const float* Wm  = (const float*)d_in[1];
  const float* Cm  = (const float*)d_in[2];
  const float* Wq  = (const float*)d_in[3];
  const float* Wk  = (const float*)d_in[4];
  const float* Wv  = (const float*)d_in[5];
  const float* Wo  = (const float*)d_in[6];
  const float* bo  = (const float*)d_in[7];
  const float* bw  = (const float*)d_in[8];
  const float* bc  = (const float*)d_in[9];
  const float* g1  = (const float*)d_in[10];
  const float* be1 = (const float*)d_in[11];
  const float* g2  = (const float*)d_in[12];
  const float* be2 = (const float*)d_in[13];
  const float* W1  = (const float*)d_in[14];
  const float* b1  = (const float*)d_in[15];
  const float* W2  = (const float*)d_in[16];
  const float* b2  = (const float*)d_in[17];

  char* ws = (char*)d_ws;
  const size_t MB = 1u << 20;
  unsigned short* xb   = (unsigned short*)(ws);            // 8MB  (later reused as x1b)
  unsigned short* Wqkv = (unsigned short*)(ws + 8  * MB);  // 6MB stacked [3072][1024]
  unsigned short* Wob  = (unsigned short*)(ws + 14 * MB);  // 2MB
  unsigned short* W1b  = (unsigned short*)(ws + 16 * MB);  // 4MB
  unsigned short* W2b  = (unsigned short*)(ws + 20 * MB);  // 4MB
  unsigned short* Qb   = (unsigned short*)(ws + 24 * MB);  // 8MB
  unsigned short* Kb   = (unsigned short*)(ws + 32 * MB);  // 8MB
  unsigned short* Vtb  = (unsigned short*)(ws + 40 * MB);  // 8MB, V TRANSPOSED [1024][4096]
  unsigned short* Obuf = (unsigned short*)(ws + 48 * MB);  // 16MB as Opart[2][4096][1024]
  float*          Lsb  = (float*)(ws + 64 * MB);           // 256KB lsum partials
  unsigned char*  Pkb  = (unsigned char*)(ws + 72 * MB);   // 16MB packed u8 W|C bias
  unsigned short* tmpb = (unsigned short*)(ws + 56 * MB);  // 8MB bf16 (Wo out, then FF2 out)
                                                           //   clobbers Opart[1] (dead)
  float*          x1f  = (float*)(ws + 24 * MB);           // 16MB (over Qb/Kb, dead by then)
  unsigned short* x1b  = (unsigned short*)(ws);            // over xb (dead)
  unsigned short* hb   = (unsigned short*)(ws + 40 * MB);  // 16MB (over Vtb/Obuf, dead)

  // 1. all conversions + u8 bias packing in ONE launch
  PrepArgs pa;
  pa.x = x; pa.wq = Wq; pa.wk = Wk; pa.wv = Wv; pa.wo = Wo; pa.w1 = W1; pa.w2 = W2;
  pa.wm = Wm; pa.cm = Cm;
  pa.xb = xb; pa.wqd = Wqkv; pa.wkd = Wqkv + 1024 * 1024; pa.wvd = Wqkv + 2048 * 1024;
  pa.wod = Wob; pa.w1d = W1b; pa.w2d = W2b; pa.pk = Pkb;
  k_prep<<<28672, 256, 0, stream>>>(pa);

  // 2. fused QKV projection: cols 0-1023 -> Qb, 1024-2047 -> Kb, 2048-3071 -> Vt^T
  k_gemm_bt<0,3,128><<<dim3(24, 32), 256, 0, stream>>>(xb, Wqkv, nullptr, Qb,
                                                       4096, 3072, 1024, 1024, Kb, Vtb);

  // 3. fused attention, split-KV (z = 2 halves), 4 blocks/CU, then combine
  k_attn<<<dim3(64, 8, 2), 256, 0, stream>>>(Qb, Kb, Vtb, Pkb, bw, bc, Obuf, Lsb);
  k_comb<<<4096, 256, 0, stream>>>(Obuf, Lsb, Obuf);

  // 4. output projection (bf16 out + bias) — BM=64: grid 512 = 2 blocks/CU
  k_gemm_bt<0,1,64><<<dim3(8, 64), 256, 0, stream>>>(Obuf, Wob, bo, tmpb, 4096, 1024, 1024, 1024);

  // 5. LN1: x1 = LN(x + attn_out)
  k_ln<<<4096, 256, 0, stream>>>(x, tmpb, g1, be1, x1f, x1b);

  // 6. FF1 with ReLU (bf16 out) — BM=64: grid 1024 = 4 blocks/CU
  k_gemm_bt<1,1,64><<<dim3(16, 64), 256, 0, stream>>>(x1b, W1b, b1, hb, 4096, 2048, 1024, 2048);

  // 7. FF2 (bf16 out + bias) — BM=64: grid 512 = 2 blocks/CU
  k_gemm_bt<0,1,64><<<dim3(8, 64), 256, 0, stream>>>(hb, W2b, b2, tmpb, 4096, 1024, 2048, 1024);

  // 8. LN2 -> d_out
  k_ln<<<4096, 256, 0, stream>>>(x1f, tmpb, g2, be2, (float*)d_out, nullptr);
}

// Round 15
// 304.861 us; speedup vs baseline: 1.0691x; 1.0157x over previous
//
#include <hip/hip_runtime.h>

typedef __attribute__((ext_vector_type(8))) short bf16x8;
typedef __attribute__((ext_vector_type(4))) float f32x4;
typedef __attribute__((ext_vector_type(4))) unsigned short u16x4;

#define GAS(p) ((const __attribute__((address_space(1))) void*)(p))
#define LAS(p) ((__attribute__((address_space(3))) void*)(p))

__device__ __forceinline__ unsigned short f2bf(float f) {
  unsigned int u = __float_as_uint(f);
  u += 0x7fffu + ((u >> 16) & 1u);
  return (unsigned short)(u >> 16);
}

__device__ __forceinline__ float bf2f(unsigned short u) {
  return __uint_as_float(((unsigned int)u) << 16);
}

__device__ __forceinline__ float fexp2(float x) {
  float r;
  asm("v_exp_f32 %0, %1" : "=v"(r) : "v"(x));
  return r;
}

// -------- fused prep: 7x f32->bf16 convert + u8 graph-bias pack, ONE launch ----------
// Conv vec4 items: x 1048576 | wq/wk/wv/wo 262144 ea | w1 524288 | w2 524288
//   -> conv total 3,145,728. Pack items 4,194,304. Grand total 7,340,032 = 28672 x 256.
struct PrepArgs {
  const float *x, *wq, *wk, *wv, *wo, *w1, *w2, *wm, *cm;
  unsigned short *xb, *wqd, *wkd, *wvd, *wod, *w1d, *w2d;
  unsigned char *pk;
};
__global__ __launch_bounds__(256) void k_prep(PrepArgs a) {
  long i = (long)blockIdx.x * 256 + threadIdx.x;  // vec4 index
  if (i >= 3145728) {                             // pack segment
    long j = i - 3145728;
    f32x4 w = *(const f32x4*)(a.wm + j * 4);
    f32x4 c = *(const f32x4*)(a.cm + j * 4);
    unsigned int o = 0;
#pragma unroll
    for (int e = 0; e < 4; ++e) {
      unsigned int v = (unsigned int)(w[e] * 127.0f + 0.5f);
      o |= (((v << 1) | (c[e] > 0.5f ? 1u : 0u)) & 0xFFu) << (8 * e);
    }
    *(unsigned int*)(a.pk + j * 4) = o;
    return;
  }
  const float* s;
  unsigned short* d;
  long j;
  if (i < 1048576)      { s = a.x;  d = a.xb;  j = i; }
  else if (i < 1310720) { s = a.wq; d = a.wqd; j = i - 1048576; }
  else if (i < 1572864) { s = a.wk; d = a.wkd; j = i - 1310720; }
  else if (i < 1835008) { s = a.wv; d = a.wvd; j = i - 1572864; }
  else if (i < 2097152) { s = a.wo; d = a.wod; j = i - 1835008; }
  else if (i < 2621440) { s = a.w1; d = a.w1d; j = i - 2097152; }
  else                  { s = a.w2; d = a.w2d; j = i - 2621440; }
  f32x4 v = *(const f32x4*)(s + j * 4);
  u16x4 o;
  o[0] = f2bf(v[0]); o[1] = f2bf(v[1]); o[2] = f2bf(v[2]); o[3] = f2bf(v[3]);
  *(u16x4*)(d + j * 4) = o;
}

// ---------------- bf16 GEMM: C[M,N] = A[M,K] * B[N,K]^T ------------------------------
// Tile BM x 128, BK=64, 4 waves in 2x2 (wave tile BM/2 x 64).
// BM=128 -> 3 blocks/CU (m114: implicit wave-overlap peaks ~3); BM=64 -> 4 blocks/CU.
// OUTMODE: 0 = f32 (+bias, relu opt), 1 = bf16 (+bias/relu opt), 2 = bf16 TRANSPOSED,
//          3 = QKV router: cols [0,1024)->C, [1024,2048)->C2, [2048,3072)->C3 transposed.
template<int RELU, int OUTMODE, int BM>
__global__ __launch_bounds__(256, (BM == 64 ? 4 : 3))
void k_gemm_bt(const unsigned short* __restrict__ A, const unsigned short* __restrict__ B,
               const float* __restrict__ bias, void* __restrict__ C,
               int M, int N, int K, int ldc,
               void* __restrict__ C2 = nullptr, void* __restrict__ C3 = nullptr)
{
  __shared__ char sA[BM * 128];
  __shared__ char sB[128 * 128];
  const int t = threadIdx.x, wv = t >> 6, ln = t & 63;
  const int lr = ln & 15, lg = ln >> 4;
  const int m0 = blockIdx.y * BM, n0 = blockIdx.x * 128;
  const int wm = wv >> 1, wn = wv & 1;
  constexpr int MF = BM / 32;   // m-fragments per wave
  f32x4 acc[MF][4] = {};
  for (int k0 = 0; k0 < K; k0 += 64) {
#pragma unroll
    for (int c2 = 0; c2 < BM / 32; ++c2) {      // A chunks
      int p = ((c2 * 4 + wv) << 10) | (ln << 4);
      int row = p >> 7, colb = p & 127;
      const char* ga = (const char*)A + ((size_t)(m0 + row) * K + k0) * 2 + (colb ^ ((row & 7) << 4));
      __builtin_amdgcn_global_load_lds(GAS(ga), LAS(sA + ((c2 * 4 + wv) << 10)), 16, 0, 0);
    }
#pragma unroll
    for (int c2 = 0; c2 < 4; ++c2) {            // B chunks
      int p = ((c2 * 4 + wv) << 10) | (ln << 4);
      int row = p >> 7, colb = p & 127;
      const char* gb = (const char*)B + ((size_t)(n0 + row) * K + k0) * 2 + (colb ^ ((row & 7) << 4));
      __builtin_amdgcn_global_load_lds(GAS(gb), LAS(sB + ((c2 * 4 + wv) << 10)), 16, 0, 0);
    }
    __syncthreads();
#pragma unroll
    for (int kk = 0; kk < 2; ++kk) {
      bf16x8 af[MF], bfr[4];
#pragma unroll
      for (int i = 0; i < MF; ++i) {
        int row = wm * (BM / 2) + i * 16 + lr;
        af[i] = *(const bf16x8*)(sA + row * 128 + ((kk * 64 + lg * 16) ^ ((row & 7) << 4)));
      }
#pragma unroll
      for (int j = 0; j < 4; ++j) {
        int row = wn * 64 + j * 16 + lr;
        bfr[j] = *(const bf16x8*)(sB + row * 128 + ((kk * 64 + lg * 16) ^ ((row & 7) << 4)));
      }
#pragma unroll
      for (int i = 0; i < MF; ++i)
#pragma unroll
        for (int j = 0; j < 4; ++j)
          acc[i][j] = __builtin_amdgcn_mfma_f32_16x16x32_bf16(af[i], bfr[j], acc[i][j], 0, 0, 0);
    }
    __syncthreads();
  }
#pragma unroll
  for (int i = 0; i < MF; ++i) {
    int m = m0 + wm * (BM / 2) + i * 16 + lg * 4;
#pragma unroll
    for (int j = 0; j < 4; ++j) {
      int n = n0 + wn * 64 + j * 16 + lr;
      if (OUTMODE == 3) {
        if (n0 < 1024) {
#pragma unroll
          for (int r = 0; r < 4; ++r)
            ((unsigned short*)C)[(size_t)(m + r) * 1024 + n] = f2bf(acc[i][j][r]);
        } else if (n0 < 2048) {
#pragma unroll
          for (int r = 0; r < 4; ++r)
            ((unsigned short*)C2)[(size_t)(m + r) * 1024 + (n - 1024)] = f2bf(acc[i][j][r]);
        } else {
          u16x4 o;
#pragma unroll
          for (int r = 0; r < 4; ++r) o[r] = f2bf(acc[i][j][r]);
          *(u16x4*)((unsigned short*)C3 + (size_t)(n - 2048) * 4096 + m) = o;
        }
      } else if (OUTMODE == 2) {
        u16x4 o;
#pragma unroll
        for (int r = 0; r < 4; ++r) o[r] = f2bf(acc[i][j][r]);
        *(u16x4*)((unsigned short*)C + (size_t)n * ldc + m) = o;
      } else {
        float bv = bias ? bias[n] : 0.f;
#pragma unroll
        for (int r = 0; r < 4; ++r) {
          float v = acc[i][j][r] + bv;
          if (RELU) v = fmaxf(v, 0.f);
          if (OUTMODE == 1) ((unsigned short*)C)[(size_t)(m + r) * ldc + n] = f2bf(v);
          else ((float*)C)[(size_t)(m + r) * ldc + n] = v;
        }
      }
    }
  }
}

// ---------------- fused flash attention, split-KV, u8 graph bias (R11 config) --------
// grid (N/64, H, 2): block = 4 waves x 16 q rows, one KV-half (2048 = 64 tiles of 32).
// K [32][256B] 8-slot swizzle; V PAIR layout [64 pairs][128B], 8-slot swizzle ->
// conflict-free vf reads. Bias 1 byte/elem (per-XCD slice L2-resident).
// Fixed-shift softmax (C=16); partial O + lsum per half, k_comb joins.
__global__ __launch_bounds__(256, 4)
void k_attn(const unsigned short* __restrict__ Qb, const unsigned short* __restrict__ Kb,
            const unsigned short* __restrict__ Vtb, const unsigned char* __restrict__ Pk,
            const float* __restrict__ bwv, const float* __restrict__ bcv,
            unsigned short* __restrict__ Opart, float* __restrict__ Ls)
{
  __shared__ char sK[2 * 8192];            // [buf][32 kv][256B d] bf16, xor-swizzled
  __shared__ char sV[2 * 8192];            // [buf][64 pairs][128B] bf16, xor-swizzled
  __shared__ unsigned short sP[4][16][44]; // pitch 44 -> disjoint bank octets per write
  const int t = threadIdx.x, wv = t >> 6, ln = t & 63;
  const int lr = ln & 15, lg = ln >> 4;
  const int h = blockIdx.y, z = blockIdx.z;
  const int q0 = blockIdx.x * 64 + wv * 16;
  const int kvb = z * 2048;
  const float L2E = 1.4426950408889634f;
  const float scaleL = 0.08838834764831845f * L2E; // (1/sqrt(128)) * log2e
  const float bw2 = bwv[h] * L2E * (1.0f / 127.0f), bc2 = bcv[h] * L2E;
  const float CL = 16.0f * L2E;

  // Q fragments (registers for whole kernel)
  bf16x8 qf[4];
#pragma unroll
  for (int kk = 0; kk < 4; ++kk)
    qf[kk] = *(const bf16x8*)(Qb + (size_t)(q0 + lr) * 1024 + h * 128 + kk * 32 + lg * 8);

  // per-row packed-bias pointers
  const unsigned char* pk[4];
#pragma unroll
  for (int r = 0; r < 4; ++r)
    pk[r] = Pk + (size_t)(q0 + lg * 4 + r) * 4096 + lr;

  f32x4 Oacc[8] = {};
  float lsum[4] = {0.f, 0.f, 0.f, 0.f};

  auto stageKV = [&](int buf, int kv) {
#pragma unroll
    for (int c2 = 0; c2 < 2; ++c2) {
      int p = ((c2 * 4 + wv) << 10) | (ln << 4);
      {
        int row = p >> 8, colb = p & 255;   // K: 32 rows x 256B
        const char* g = (const char*)Kb + ((size_t)(kv + row) * 1024 + h * 128) * 2 + (colb ^ ((row & 7) << 4));
        __builtin_amdgcn_global_load_lds(GAS(g), LAS(sK + buf * 8192 + p), 16, 0, 0);
      }
      {
        // V pair layout: pair=p>>7; slot s -> d = 2*pair+(s>>2), kv-chunk (s&3)*8
        int pair = p >> 7;
        int s = ((p & 127) ^ ((pair & 7) << 4)) >> 4;
        int d = 2 * pair + (s >> 2);
        int kvo = (s & 3) * 8;
        const char* g = (const char*)Vtb + ((size_t)(h * 128 + d) * 4096 + kv + kvo) * 2;
        __builtin_amdgcn_global_load_lds(GAS(g), LAS(sV + buf * 8192 + p), 16, 0, 0);
      }
    }
  };

  // prologue
  stageKV(0, kvb);
  __syncthreads();

  for (int it = 0; it < 64; ++it) {
    const int cur = it & 1;
    const int kv0 = kvb + (it << 5);
    const char* sKc = sK + cur * 8192;
    const char* sVc = sV + cur * 8192;

    // u8 bias loads for THIS tile, issued first (latency hides under QK^T MFMA)
    unsigned char pv[2][4];
#pragma unroll
    for (int j = 0; j < 2; ++j)
#pragma unroll
      for (int r = 0; r < 4; ++r)
        pv[j][r] = pk[r][kv0 + j * 16];

    // prefetch next K/V tile into the other buffers
    if (it < 63) stageKV(cur ^ 1, kv0 + 32);

    // S = Q K^T  (4 d-ksteps x 2 kv-ntiles)
    f32x4 S[2] = {};
    __builtin_amdgcn_s_setprio(1);
#pragma unroll
    for (int kk = 0; kk < 4; ++kk)
#pragma unroll
      for (int j = 0; j < 2; ++j) {
        int row = j * 16 + lr;
        bf16x8 kf = *(const bf16x8*)(sKc + row * 256 + ((kk * 64 + lg * 16) ^ ((row & 7) << 4)));
        S[j] = __builtin_amdgcn_mfma_f32_16x16x32_bf16(qf[kk], kf, S[j], 0, 0, 0);
      }
    __builtin_amdgcn_s_setprio(0);

    // softmax numerators: decode u8 bias, p = exp2(S*scaleL + fb); denominator
#pragma unroll
    for (int j = 0; j < 2; ++j)
#pragma unroll
      for (int r = 0; r < 4; ++r) {
        unsigned int v = pv[j][r];
        float w = (float)(v >> 1);
        float fb = fmaf(w, bw2, ((v & 1u) ? bc2 : 0.0f) - CL);
        float p = fexp2(fmaf(S[j][r], scaleL, fb));
        lsum[r] += p;
        sP[wv][lg * 4 + r][j * 16 + lr] = f2bf(p);
      }

    // O += P V   (8 d-ntiles, single 32-k step) — conflict-free pair-layout reads
    __builtin_amdgcn_s_setprio(1);
    {
      bf16x8 pf = *(const bf16x8*)((const char*)sP[wv] + (size_t)lr * 88 + lg * 16);
#pragma unroll
      for (int n = 0; n < 8; ++n) {
        int row = n * 16 + lr;
        int pair = row >> 1;
        int slot = (((row & 1) << 2) + lg) ^ (pair & 7);
        bf16x8 vf = *(const bf16x8*)(sVc + pair * 128 + slot * 16);
        Oacc[n] = __builtin_amdgcn_mfma_f32_16x16x32_bf16(pf, vf, Oacc[n], 0, 0, 0);
      }
    }
    __builtin_amdgcn_s_setprio(0);

    __syncthreads();  // staging(t+1) drained (full-iter cover); cur-buffer reads done
  }

  // partial denominator reduce across the 16 lanes of each row group
#pragma unroll
  for (int r = 0; r < 4; ++r) {
#pragma unroll
    for (int msk = 1; msk < 16; msk <<= 1) lsum[r] += __shfl_xor(lsum[r], msk, 64);
  }

  // store unnormalized bf16 partial O + f32 partial lsum
  unsigned short* Op = Opart + (size_t)z * 4194304;
#pragma unroll
  for (int n = 0; n < 8; ++n)
#pragma unroll
    for (int r = 0; r < 4; ++r) {
      int qg = q0 + lg * 4 + r;
      Op[(size_t)qg * 1024 + h * 128 + n * 16 + lr] = f2bf(Oacc[n][r]);
    }
  if (lr == 0) {
#pragma unroll
    for (int r = 0; r < 4; ++r)
      Ls[(size_t)(z * 8 + h) * 4096 + q0 + lg * 4 + r] = lsum[r];
  }
}

// ---------------- combine split-KV partials: O = (O0+O1)/(l0+l1) (in-place safe) -----
__global__ __launch_bounds__(256)
void k_comb(const unsigned short* __restrict__ P, const float* __restrict__ Ls,
            unsigned short* __restrict__ out)
{
  const int q = blockIdx.x, t = threadIdx.x;
  const int h = t >> 5;
  float l = Ls[(size_t)h * 4096 + q] + Ls[(size_t)(8 + h) * 4096 + q];
  float inv = 1.0f / l;
  size_t o = (size_t)q * 1024 + t * 4;
  u16x4 a = *(const u16x4*)(P + o);
  u16x4 b = *(const u16x4*)(P + 4194304 + o);
  u16x4 c;
#pragma unroll
  for (int e = 0; e < 4; ++e) c[e] = f2bf((bf2f(a[e]) + bf2f(b[e])) * inv);
  *(u16x4*)(out + o) = c;
}

// ---- fused residual + LayerNorm: resid (f32 or bf16) + bf16 delta -> f32/bf16 out ---
template<int RBF16>
__global__ __launch_bounds__(256, 4)
void k_ln(const void* __restrict__ resid, const unsigned short* __restrict__ delta,
          const float* __restrict__ g, const float* __restrict__ b,
          float* __restrict__ outf, unsigned short* __restrict__ outb)
{
  const int row = blockIdx.x, t = threadIdx.x;
  const unsigned short* pd = delta + (size_t)row * 1024;
  u16x4 d = *(const u16x4*)(pd + t * 4);
  f32x4 x;
  if (RBF16) {
    u16x4 a = *(const u16x4*)((const unsigned short*)resid + (size_t)row * 1024 + t * 4);
#pragma unroll
    for (int e = 0; e < 4; ++e) x[e] = bf2f(a[e]) + bf2f(d[e]);
  } else {
    f32x4 a = *(const f32x4*)((const float*)resid + (size_t)row * 1024 + t * 4);
#pragma unroll
    for (int e = 0; e < 4; ++e) x[e] = a[e] + bf2f(d[e]);
  }
  float s = x[0] + x[1] + x[2] + x[3];
  float ss = x[0]*x[0] + x[1]*x[1] + x[2]*x[2] + x[3]*x[3];
#pragma unroll
  for (int msk = 1; msk < 64; msk <<= 1) {
    s += __shfl_xor(s, msk, 64);
    ss += __shfl_xor(ss, msk, 64);
  }
  __shared__ float red[8];
  if ((t & 63) == 0) { red[(t >> 6) * 2] = s; red[(t >> 6) * 2 + 1] = ss; }
  __syncthreads();
  s = red[0] + red[2] + red[4] + red[6];
  ss = red[1] + red[3] + red[5] + red[7];
  float mu = s * (1.f / 1024.f);
  float var = ss * (1.f / 1024.f) - mu * mu;
  float rstd = rsqrtf(var + 1e-5f);
#pragma unroll
  for (int e = 0; e < 4; ++e) {
    int c = t * 4 + e;
    float y = (x[e] - mu) * rstd * g[c] + b[c];
    if (outf) outf[(size_t)row * 1024 + c] = y;
    if (outb) outb[(size_t)row * 1024 + c] = f2bf(y);
  }
}

// ---------------- launch ----------------
extern "C" void kernel_launch(void* const* d_in, const int* in_sizes, int n_in,
                              void* d_out, int out_size, void* d_ws, size_t ws_size,
                              hipStream_t stream) {
  const float* x   = (const float*)d_in[0];
  const float* Wm  = (const float*)d_in[1];
  const float* Cm  = (const float*)d_in[2];
  const float* Wq  = (const float*)d_in[3];
  const float* Wk  = (const float*)d_in[4];
  const float* Wv  = (const float*)d_in[5];
  const float* Wo  = (const float*)d_in[6];
  const float* bo  = (const float*)d_in[7];
  const float* bw  = (const float*)d_in[8];
  const float* bc  = (const float*)d_in[9];
  const float* g1  = (const float*)d_in[10];
  const float* be1 = (const float*)d_in[11];
  const float* g2  = (const float*)d_in[12];
  const float* be2 = (const float*)d_in[13];
  const float* W1  = (const float*)d_in[14];
  const float* b1  = (const float*)d_in[15];
  const float* W2  = (const float*)d_in[16];
  const float* b2  = (const float*)d_in[17];

  char* ws = (char*)d_ws;
  const size_t MB = 1u << 20;
  unsigned short* xb   = (unsigned short*)(ws);            // 8MB  (later reused as x1b)
  unsigned short* Wqkv = (unsigned short*)(ws + 8  * MB);  // 6MB stacked [3072][1024]
  unsigned short* Wob  = (unsigned short*)(ws + 14 * MB);  // 2MB
  unsigned short* W1b  = (unsigned short*)(ws + 16 * MB);  // 4MB
  unsigned short* W2b  = (unsigned short*)(ws + 20 * MB);  // 4MB
  unsigned short* Qb   = (unsigned short*)(ws + 24 * MB);  // 8MB
  unsigned short* Kb   = (unsigned short*)(ws + 32 * MB);  // 8MB
  unsigned short* Vtb  = (unsigned short*)(ws + 40 * MB);  // 8MB, V TRANSPOSED [1024][4096]
  unsigned short* Obuf = (unsigned short*)(ws + 48 * MB);  // 16MB as Opart[2][4096][1024]
  float*          Lsb  = (float*)(ws + 64 * MB);           // 256KB lsum partials
  unsigned char*  Pkb  = (unsigned char*)(ws + 72 * MB);   // 16MB packed u8 W|C bias
  unsigned short* tmpb = (unsigned short*)(ws + 56 * MB);  // 8MB bf16 (Wo out, then FF2 out)
                                                           //   clobbers Opart[1] (dead)
  unsigned short* x1b  = (unsigned short*)(ws);            // over xb (dead after QKV)
  unsigned short* hb   = (unsigned short*)(ws + 40 * MB);  // 16MB (over Vtb/Obuf, dead)

  // 1. all conversions + u8 bias packing in ONE launch
  PrepArgs pa;
  pa.x = x; pa.wq = Wq; pa.wk = Wk; pa.wv = Wv; pa.wo = Wo; pa.w1 = W1; pa.w2 = W2;
  pa.wm = Wm; pa.cm = Cm;
  pa.xb = xb; pa.wqd = Wqkv; pa.wkd = Wqkv + 1024 * 1024; pa.wvd = Wqkv + 2048 * 1024;
  pa.wod = Wob; pa.w1d = W1b; pa.w2d = W2b; pa.pk = Pkb;
  k_prep<<<28672, 256, 0, stream>>>(pa);

  // 2. fused QKV projection: cols 0-1023 -> Qb, 1024-2047 -> Kb, 2048-3071 -> Vt^T
  k_gemm_bt<0,3,128><<<dim3(24, 32), 256, 0, stream>>>(xb, Wqkv, nullptr, Qb,
                                                       4096, 3072, 1024, 1024, Kb, Vtb);

  // 3. fused attention, split-KV (z = 2 halves), 4 blocks/CU, then combine
  k_attn<<<dim3(64, 8, 2), 256, 0, stream>>>(Qb, Kb, Vtb, Pkb, bw, bc, Obuf, Lsb);
  k_comb<<<4096, 256, 0, stream>>>(Obuf, Lsb, Obuf);

  // 4. output projection (bf16 out + bias) — BM=64: grid 512 = 2 blocks/CU
  k_gemm_bt<0,1,64><<<dim3(8, 64), 256, 0, stream>>>(Obuf, Wob, bo, tmpb, 4096, 1024, 1024, 1024);

  // 5. LN1: x1 = LN(x + attn_out) -> bf16 only
  k_ln<0><<<4096, 256, 0, stream>>>(x, tmpb, g1, be1, nullptr, x1b);

  // 6. FF1 with ReLU (bf16 out) — BM=64: grid 1024 = 4 blocks/CU
  k_gemm_bt<1,1,64><<<dim3(16, 64), 256, 0, stream>>>(x1b, W1b, b1, hb, 4096, 2048, 1024, 2048);

  // 7. FF2 (bf16 out + bias) — BM=64: grid 512 = 2 blocks/CU
  k_gemm_bt<0,1,64><<<dim3(8, 64), 256, 0, stream>>>(hb, W2b, b2, tmpb, 4096, 1024, 2048, 1024);

  // 8. LN2 (bf16 residual) -> d_out
  k_ln<1><<<4096, 256, 0, stream>>>(x1b, tmpb, g2, be2, (float*)d_out, nullptr);
}